// Round 3
// baseline (151.639 us; speedup 1.0000x reference)
//
#include <hip/hip_runtime.h>
#include <math.h>

// CapLayer fused: grouped 1x1 conv + 3-iter dynamic routing.
// One block per (b, j). Each thread owns i = 3t..3t+2 (single group g = t/12),
// pred[16][3] in registers. W j-slice staged in LDS, read d-outer (once per d).
// launch_bounds(384,5): VGPR cap ~102 -> no spill (algorithm needs ~90).

#define G_    32
#define IND_  8
#define J_    10
#define D_    16
#define S_    36
#define ITOT_ (G_ * S_)     // 1152
#define NT_   384
#define QN_   3
#define NW_   (NT_ / 64)    // 6

__global__ __launch_bounds__(NT_, 5) void caps_route_kernel(
    const float* __restrict__ x,     // (b, g*8+id, s)
    const float* __restrict__ Wt,    // (g, j*16+d, id)
    const float* __restrict__ bias,  // g*160 + j*16 + d
    float* __restrict__ out)         // (b, j, d)
{
    // XCD swizzle: consecutive bj (same b, all j) land on one XCD for L2 x-reuse
    const int B = blockIdx.x;
    const int nwg = gridDim.x;
    const int bj = ((nwg & 7) == 0) ? (B & 7) * (nwg >> 3) + (B >> 3) : B;
    const int b = bj / J_;
    const int j = bj - b * J_;
    const int t = threadIdx.x;
    const int lane = t & 63;
    const int wid = t >> 6;

    __shared__ __align__(16) float Ws[G_ * D_ * IND_];   // 16 KB (g,d,id)
    __shared__ __align__(16) float bs_[G_ * D_];         // 2 KB
    __shared__ __align__(16) float pt[2][NW_][D_];
    __shared__ float sm[2][NW_];
    __shared__ __align__(16) float sv[2][D_];

    // ---- this thread's group and x preload (24 scalar loads, L2-resident) ----
    const int g  = t / 12;              // i0 = 3t, g = 3t/36
    const int s0 = 3 * (t - g * 12);
    const float* xb = x + (size_t)b * (G_ * IND_ * S_) + g * (IND_ * S_) + s0;
    float xv[QN_][IND_];
    #pragma unroll
    for (int id = 0; id < IND_; ++id) {
        #pragma unroll
        for (int q = 0; q < QN_; ++q) xv[q][id] = xb[id * S_ + q];
    }

    // ---- stage W j-slice (contiguous 128 floats per g) + bias ----
    for (int idx = t; idx < (G_ * D_ * IND_) / 4; idx += NT_) {
        const int gg = idx >> 5, r = idx & 31;
        ((float4*)Ws)[idx] =
            *(const float4*)(Wt + (size_t)gg * (J_ * D_ * IND_) + j * (D_ * IND_) + r * 4);
    }
    for (int idx = t; idx < G_ * D_; idx += NT_) {
        const int gg = idx >> 4, d = idx & 15;
        bs_[idx] = bias[gg * (J_ * D_) + j * D_ + d];
    }
    __syncthreads();

    // ---- pred[d][q]: d-outer, W read once per d ----
    float pred[D_][QN_];
    {
        const float4* wp = (const float4*)(Ws + g * (D_ * IND_));
        const float*  bp = bs_ + g * D_;
        #pragma unroll
        for (int d = 0; d < D_; ++d) {
            const float4 w0 = wp[d * 2 + 0];
            const float4 w1 = wp[d * 2 + 1];
            const float  bv = bp[d];
            #pragma unroll
            for (int q = 0; q < QN_; ++q) {
                pred[d][q] = bv
                    + w0.x * xv[q][0] + w0.y * xv[q][1] + w0.z * xv[q][2] + w0.w * xv[q][3]
                    + w1.x * xv[q][4] + w1.y * xv[q][5] + w1.z * xv[q][6] + w1.w * xv[q][7];
            }
        }
    }

    // ---- routing ----
    float b_loc[QN_] = {0.f, 0.f, 0.f};
    const float EPS = 2.220446049250313e-16f;
    const bool hib5 = (lane & 32) != 0, hib4 = (lane & 16) != 0;
    const bool hib3 = (lane & 8) != 0,  hib2 = (lane & 4) != 0;

    #pragma unroll 1
    for (int it = 0; it < 3; ++it) {
        const int k = it & 1;

        // un-normalized weights e[q]; wave sum of exp
        float e[QN_], se;
        if (it == 0) {
            e[0] = e[1] = e[2] = 1.f;
            se = 3.f;
        } else {
            se = 0.f;
            #pragma unroll
            for (int q = 0; q < QN_; ++q) { e[q] = __expf(b_loc[q]); se += e[q]; }
        }
        #pragma unroll
        for (int off = 32; off >= 1; off >>= 1) se += __shfl_xor(se, off);
        if (lane == 0) sm[k][wid] = se;

        // weighted per-thread partials
        float p[D_];
        #pragma unroll
        for (int d = 0; d < D_; ++d)
            p[d] = e[0] * pred[d][0] + e[1] * pred[d][1] + e[2] * pred[d][2];

        // packed butterfly: one shfl per exchange; lane l ends with d=(l>>2)&15
        float q8[8];
        #pragma unroll
        for (int dd = 0; dd < 8; ++dd) {
            const float snd = hib5 ? p[dd] : p[dd + 8];
            const float r   = __shfl_xor(snd, 32);
            q8[dd] = (hib5 ? p[dd + 8] : p[dd]) + r;
        }
        float q4[4];
        #pragma unroll
        for (int dd = 0; dd < 4; ++dd) {
            const float snd = hib4 ? q8[dd] : q8[dd + 4];
            const float r   = __shfl_xor(snd, 16);
            q4[dd] = (hib4 ? q8[dd + 4] : q8[dd]) + r;
        }
        float q2[2];
        #pragma unroll
        for (int dd = 0; dd < 2; ++dd) {
            const float snd = hib3 ? q4[dd] : q4[dd + 2];
            const float r   = __shfl_xor(snd, 8);
            q2[dd] = (hib3 ? q4[dd + 2] : q4[dd]) + r;
        }
        float q1;
        {
            const float snd = hib2 ? q2[0] : q2[1];
            const float r   = __shfl_xor(snd, 4);
            q1 = (hib2 ? q2[1] : q2[0]) + r;
        }
        q1 += __shfl_xor(q1, 2);
        q1 += __shfl_xor(q1, 1);
        if ((lane & 3) == 0) pt[k][wid][lane >> 2] = q1;
        __syncthreads();                                   // barrier A

        const float denom = sm[k][0] + sm[k][1] + sm[k][2] + sm[k][3] + sm[k][4] + sm[k][5];

        if (t < D_) {
            sv[k][t] = pt[k][0][t] + pt[k][1][t] + pt[k][2][t]
                     + pt[k][3][t] + pt[k][4][t] + pt[k][5][t];
        }
        __syncthreads();                                   // barrier B

        const float4 s0v = ((const float4*)sv[k])[0];
        const float4 s1v = ((const float4*)sv[k])[1];
        const float4 s2v = ((const float4*)sv[k])[2];
        const float4 s3v = ((const float4*)sv[k])[3];
        float ssq = s0v.x * s0v.x + s0v.y * s0v.y + s0v.z * s0v.z + s0v.w * s0v.w
                  + s1v.x * s1v.x + s1v.y * s1v.y + s1v.z * s1v.z + s1v.w * s1v.w
                  + s2v.x * s2v.x + s2v.y * s2v.y + s2v.z * s2v.z + s2v.w * s2v.w
                  + s3v.x * s3v.x + s3v.y * s3v.y + s3v.z * s3v.z + s3v.w * s3v.w;
        const float alpha = 1.0f / denom;
        const float n2 = ssq * alpha * alpha;
        const float norm = sqrtf(n2);
        const float coeff = (n2 / (1.f + n2)) / (norm + EPS);
        const float beta = alpha * coeff;   // v[d] = sv[d] * beta

        if (it < 2) {
            #pragma unroll
            for (int q = 0; q < QN_; ++q) {
                float dot =
                    s0v.x * pred[0][q]  + s0v.y * pred[1][q]  + s0v.z * pred[2][q]  + s0v.w * pred[3][q]
                  + s1v.x * pred[4][q]  + s1v.y * pred[5][q]  + s1v.z * pred[6][q]  + s1v.w * pred[7][q]
                  + s2v.x * pred[8][q]  + s2v.y * pred[9][q]  + s2v.z * pred[10][q] + s2v.w * pred[11][q]
                  + s3v.x * pred[12][q] + s3v.y * pred[13][q] + s3v.z * pred[14][q] + s3v.w * pred[15][q];
                b_loc[q] += beta * dot;
            }
        } else {
            if (t < D_) out[(size_t)bj * D_ + t] = sv[k][t] * beta;
        }
    }
}

extern "C" void kernel_launch(void* const* d_in, const int* in_sizes, int n_in,
                              void* d_out, int out_size, void* d_ws, size_t ws_size,
                              hipStream_t stream) {
    const float* x    = (const float*)d_in[0];
    const float* Wt   = (const float*)d_in[1];
    const float* bias = (const float*)d_in[2];
    float* out        = (float*)d_out;

    const int bs = in_sizes[0] / (G_ * IND_ * S_);   // 256
    dim3 grid(bs * J_);
    dim3 block(NT_);
    caps_route_kernel<<<grid, block, 0, stream>>>(x, Wt, bias, out);
}

// Round 4
// 71.796 us; speedup vs baseline: 2.1121x; 2.1121x over previous
//
#include <hip/hip_runtime.h>
#include <math.h>

// CapLayer fused: grouped 1x1 conv + 3-iter dynamic routing.
// One block per (b, j). Each thread owns i = 3t..3t+2 (single group g = t/12),
// pred[16][3] in registers (~80 VGPR working set -> NO launch_bounds min-waves:
// R2/R3 showed any cap (40/48 VGPR) forces pred to scratch, 264-353 MB spill
// traffic. Let allocator pick (~90, no spill, 3 blocks/CU).
// Ws padded to 132 f/group: unpadded 512B stride = 6-way bank conflict on
// every ds_read_b128 (measured 3.9M conflicts/dispatch).

#define G_     32
#define IND_   8
#define J_     10
#define D_     16
#define S_     36
#define ITOT_  (G_ * S_)     // 1152
#define NT_    384
#define QN_    3
#define NW_    (NT_ / 64)    // 6
#define WPAD_  132           // padded per-group W stride (floats), 16B-aligned
#define BPAD_  17

__global__ __launch_bounds__(NT_) void caps_route_kernel(
    const float* __restrict__ x,     // (b, g*8+id, s)
    const float* __restrict__ Wt,    // (g, j*16+d, id)
    const float* __restrict__ bias,  // g*160 + j*16 + d
    float* __restrict__ out)         // (b, j, d)
{
    // XCD swizzle: consecutive bj (same b, all j) land on one XCD for L2 x-reuse
    const int B = blockIdx.x;
    const int nwg = gridDim.x;
    const int bj = ((nwg & 7) == 0) ? (B & 7) * (nwg >> 3) + (B >> 3) : B;
    const int b = bj / J_;
    const int j = bj - b * J_;
    const int t = threadIdx.x;
    const int lane = t & 63;
    const int wid = t >> 6;

    __shared__ __align__(16) float Ws[G_ * WPAD_];   // 16.9 KB, (g, d*8+id) padded
    __shared__ float bs_[G_ * BPAD_];                // 2.2 KB
    __shared__ __align__(16) float pt[2][NW_][D_];
    __shared__ float sm[2][NW_];
    __shared__ __align__(16) float sv[2][D_];

    const int g  = t / 12;              // i0 = 3t
    const int s0 = 3 * (t - g * 12);
    const float* xb = x + (size_t)b * (G_ * IND_ * S_) + g * (IND_ * S_) + s0;

    // ---- stage W j-slice (contiguous 128 floats per g, padded dst) + bias ----
    for (int idx = t; idx < G_ * 32; idx += NT_) {
        const int gg = idx >> 5, r = idx & 31;
        ((float4*)(Ws + gg * WPAD_))[r] =
            *(const float4*)(Wt + (size_t)gg * (J_ * D_ * IND_) + j * (D_ * IND_) + r * 4);
    }
    for (int idx = t; idx < G_ * D_; idx += NT_) {
        const int gg = idx >> 4, d = idx & 15;
        bs_[gg * BPAD_ + d] = bias[gg * (J_ * D_) + j * D_ + d];
    }
    __syncthreads();

    // ---- pred[d][q]: id-blocked (4 at a time) to cap register pressure ----
    float pred[D_][QN_];
    {
        const float* bp = bs_ + g * BPAD_;
        #pragma unroll
        for (int d = 0; d < D_; ++d) {
            const float bv = bp[d];
            pred[d][0] = bv; pred[d][1] = bv; pred[d][2] = bv;
        }
        const float4* wp = (const float4*)(Ws + g * WPAD_);
        #pragma unroll
        for (int h = 0; h < 2; ++h) {
            float xq[QN_][4];
            #pragma unroll
            for (int ii = 0; ii < 4; ++ii) {
                #pragma unroll
                for (int q = 0; q < QN_; ++q)
                    xq[q][ii] = xb[(4 * h + ii) * S_ + q];
            }
            #pragma unroll
            for (int d = 0; d < D_; ++d) {
                const float4 w = wp[d * 2 + h];
                #pragma unroll
                for (int q = 0; q < QN_; ++q)
                    pred[d][q] += w.x * xq[q][0] + w.y * xq[q][1]
                                + w.z * xq[q][2] + w.w * xq[q][3];
            }
        }
    }

    // ---- routing ----
    float b_loc[QN_] = {0.f, 0.f, 0.f};
    const float EPS = 2.220446049250313e-16f;
    const bool hib5 = (lane & 32) != 0, hib4 = (lane & 16) != 0;
    const bool hib3 = (lane & 8) != 0,  hib2 = (lane & 4) != 0;

    #pragma unroll 1
    for (int it = 0; it < 3; ++it) {
        const int k = it & 1;

        float e[QN_], se;
        if (it == 0) {
            e[0] = e[1] = e[2] = 1.f;
            se = 3.f;
        } else {
            se = 0.f;
            #pragma unroll
            for (int q = 0; q < QN_; ++q) { e[q] = __expf(b_loc[q]); se += e[q]; }
        }
        #pragma unroll
        for (int off = 32; off >= 1; off >>= 1) se += __shfl_xor(se, off);
        if (lane == 0) sm[k][wid] = se;

        float p[D_];
        #pragma unroll
        for (int d = 0; d < D_; ++d)
            p[d] = e[0] * pred[d][0] + e[1] * pred[d][1] + e[2] * pred[d][2];

        // packed butterfly: one shfl per exchange; lane l ends with d = l>>2
        float q8[8];
        #pragma unroll
        for (int dd = 0; dd < 8; ++dd) {
            const float snd = hib5 ? p[dd] : p[dd + 8];
            const float r   = __shfl_xor(snd, 32);
            q8[dd] = (hib5 ? p[dd + 8] : p[dd]) + r;
        }
        float q4[4];
        #pragma unroll
        for (int dd = 0; dd < 4; ++dd) {
            const float snd = hib4 ? q8[dd] : q8[dd + 4];
            const float r   = __shfl_xor(snd, 16);
            q4[dd] = (hib4 ? q8[dd + 4] : q8[dd]) + r;
        }
        float q2[2];
        #pragma unroll
        for (int dd = 0; dd < 2; ++dd) {
            const float snd = hib3 ? q4[dd] : q4[dd + 2];
            const float r   = __shfl_xor(snd, 8);
            q2[dd] = (hib3 ? q4[dd + 2] : q4[dd]) + r;
        }
        float q1;
        {
            const float snd = hib2 ? q2[0] : q2[1];
            const float r   = __shfl_xor(snd, 4);
            q1 = (hib2 ? q2[1] : q2[0]) + r;
        }
        q1 += __shfl_xor(q1, 2);
        q1 += __shfl_xor(q1, 1);
        if ((lane & 3) == 0) pt[k][wid][lane >> 2] = q1;
        __syncthreads();                                   // barrier A

        const float denom = sm[k][0] + sm[k][1] + sm[k][2] + sm[k][3] + sm[k][4] + sm[k][5];

        if (t < D_) {
            sv[k][t] = pt[k][0][t] + pt[k][1][t] + pt[k][2][t]
                     + pt[k][3][t] + pt[k][4][t] + pt[k][5][t];
        }
        __syncthreads();                                   // barrier B

        const float4 s0v = ((const float4*)sv[k])[0];
        const float4 s1v = ((const float4*)sv[k])[1];
        const float4 s2v = ((const float4*)sv[k])[2];
        const float4 s3v = ((const float4*)sv[k])[3];
        float ssq = s0v.x * s0v.x + s0v.y * s0v.y + s0v.z * s0v.z + s0v.w * s0v.w
                  + s1v.x * s1v.x + s1v.y * s1v.y + s1v.z * s1v.z + s1v.w * s1v.w
                  + s2v.x * s2v.x + s2v.y * s2v.y + s2v.z * s2v.z + s2v.w * s2v.w
                  + s3v.x * s3v.x + s3v.y * s3v.y + s3v.z * s3v.z + s3v.w * s3v.w;
        const float alpha = 1.0f / denom;
        const float n2 = ssq * alpha * alpha;
        const float norm = sqrtf(n2);
        const float coeff = (n2 / (1.f + n2)) / (norm + EPS);
        const float beta = alpha * coeff;   // v[d] = sv[d] * beta

        if (it < 2) {
            #pragma unroll
            for (int q = 0; q < QN_; ++q) {
                float dot =
                    s0v.x * pred[0][q]  + s0v.y * pred[1][q]  + s0v.z * pred[2][q]  + s0v.w * pred[3][q]
                  + s1v.x * pred[4][q]  + s1v.y * pred[5][q]  + s1v.z * pred[6][q]  + s1v.w * pred[7][q]
                  + s2v.x * pred[8][q]  + s2v.y * pred[9][q]  + s2v.z * pred[10][q] + s2v.w * pred[11][q]
                  + s3v.x * pred[12][q] + s3v.y * pred[13][q] + s3v.z * pred[14][q] + s3v.w * pred[15][q];
                b_loc[q] += beta * dot;
            }
        } else {
            if (t < D_) out[(size_t)bj * D_ + t] = sv[k][t] * beta;
        }
    }
}

extern "C" void kernel_launch(void* const* d_in, const int* in_sizes, int n_in,
                              void* d_out, int out_size, void* d_ws, size_t ws_size,
                              hipStream_t stream) {
    const float* x    = (const float*)d_in[0];
    const float* Wt   = (const float*)d_in[1];
    const float* bias = (const float*)d_in[2];
    float* out        = (float*)d_out;

    const int bs = in_sizes[0] / (G_ * IND_ * S_);   // 256
    dim3 grid(bs * J_);
    dim3 block(NT_);
    caps_route_kernel<<<grid, block, 0, stream>>>(x, Wt, bias, out);
}